// Round 10
// baseline (5319.430 us; speedup 1.0000x reference)
//
#include <hip/hip_runtime.h>
#include <hip/hip_bf16.h>

typedef __bf16 bf16x8 __attribute__((ext_vector_type(8)));
typedef float  f32x4  __attribute__((ext_vector_type(4)));
typedef float  f32x8  __attribute__((ext_vector_type(8)));
typedef int    i32x4  __attribute__((ext_vector_type(4)));

#define T_LEN 1024
#define DD    512
#define HH    512
#define NBLK  64     // 64 consumer blocks x 8 h-cols = 512 = H (+64 producers)
#define DEPTH 8      // ring depth (steps ahead); ring = 64*8*4KB = 2 MB in d_ws
#define FSTRIDE 8    // progress-word spacing: 8 uints = 32 B

__device__ __forceinline__ f32x4 mfma16(bf16x8 a, bf16x8 b, f32x4 c) {
    return __builtin_amdgcn_mfma_f32_16x16x32_bf16(a, b, c, 0, 0, 0);
}
__device__ __forceinline__ float sigmf_(float v) { return 1.f / (1.f + __expf(-v)); }
__device__ __forceinline__ float tanhf_(float v) { return 1.f - 2.f / (1.f + __expf(2.f * v)); }
__device__ __forceinline__ bf16x8 cvt8(f32x8 v) {
    bf16x8 r;
    #pragma unroll
    for (int j = 0; j < 8; ++j) r[j] = (__bf16)v[j];
    return r;
}

// Raw workgroup barrier WITHOUT the __syncthreads vmcnt(0) drain.
// lgkmcnt(0) preserves LDS write->read ordering across the barrier; VMEM
// store acks ride until the next poll's vmcnt(0), overlapping its load RTT.
__device__ __forceinline__ void lds_barrier() {
    asm volatile("s_waitcnt lgkmcnt(0)" ::: "memory");
    __builtin_amdgcn_s_barrier();
}

// Combined poll: 1 ring load + 16 h-frag loads, ONE round-trip, all sc1.
// Data-is-the-flag on BOTH streams: h-stash bf16 units (+0 remapped 0x0001)
// and ring f32 words (0x0 remapped 0x00000001).
__device__ __forceinline__ void poll17(const unsigned short* p, const float* rp,
                                       i32x4 f[16], i32x4* rv) {
    for (;;) {
        asm volatile(
            "global_load_dwordx4 %16, %18, off sc1\n\t"
            "global_load_dwordx4 %0, %17, off sc1\n\t"
            "global_load_dwordx4 %1, %17, off offset:64 sc1\n\t"
            "global_load_dwordx4 %2, %17, off offset:128 sc1\n\t"
            "global_load_dwordx4 %3, %17, off offset:192 sc1\n\t"
            "global_load_dwordx4 %4, %17, off offset:256 sc1\n\t"
            "global_load_dwordx4 %5, %17, off offset:320 sc1\n\t"
            "global_load_dwordx4 %6, %17, off offset:384 sc1\n\t"
            "global_load_dwordx4 %7, %17, off offset:448 sc1\n\t"
            "global_load_dwordx4 %8, %17, off offset:512 sc1\n\t"
            "global_load_dwordx4 %9, %17, off offset:576 sc1\n\t"
            "global_load_dwordx4 %10, %17, off offset:640 sc1\n\t"
            "global_load_dwordx4 %11, %17, off offset:704 sc1\n\t"
            "global_load_dwordx4 %12, %17, off offset:768 sc1\n\t"
            "global_load_dwordx4 %13, %17, off offset:832 sc1\n\t"
            "global_load_dwordx4 %14, %17, off offset:896 sc1\n\t"
            "global_load_dwordx4 %15, %17, off offset:960 sc1\n\t"
            "s_waitcnt vmcnt(0)"
            : "=&v"(f[0]), "=&v"(f[1]), "=&v"(f[2]), "=&v"(f[3]),
              "=&v"(f[4]), "=&v"(f[5]), "=&v"(f[6]), "=&v"(f[7]),
              "=&v"(f[8]), "=&v"(f[9]), "=&v"(f[10]), "=&v"(f[11]),
              "=&v"(f[12]), "=&v"(f[13]), "=&v"(f[14]), "=&v"(f[15]),
              "=&v"(*rv)
            : "v"(p), "v"(rp)
            : "memory");
        unsigned mn = 0xffffffffu;
        #pragma unroll
        for (int kk = 0; kk < 16; ++kk) {
            mn = min(mn, (unsigned)f[kk][0] & 0xffffu);   // lo u16 of 1st 8-B unit
            mn = min(mn, (unsigned)f[kk][2] & 0xffffu);   // lo u16 of 2nd 8-B unit
        }
        int ok = (mn != 0u) & ((*rv)[0] != 0) & ((*rv)[2] != 0);
        if (__all(ok)) break;
        __builtin_amdgcn_s_sleep(1);
    }
}

// ring-only poll (t==0: h comes from h0 input, only xW needs the ring)
__device__ __forceinline__ i32x4 poll_ring(const float* rp) {
    i32x4 rv;
    for (;;) {
        asm volatile(
            "global_load_dwordx4 %0, %1, off sc1\n\t"
            "s_waitcnt vmcnt(0)"
            : "=&v"(rv) : "v"(rp) : "memory");
        if (__all((rv[0] != 0) & (rv[2] != 0))) break;
        __builtin_amdgcn_s_sleep(1);
    }
    return rv;
}

__device__ __forceinline__ void xpart_mfma(const float* xr, const bf16x8* wbh, const bf16x8* wbl,
                                           f32x4& ac0, f32x4& ac1, f32x4& ac2, f32x4& ac3) {
    #pragma unroll
    for (int kk = 0; kk < 16; ++kk) {
        bf16x8 av = cvt8(*(const f32x8*)(xr + kk * 32));
        if (kk & 1) { ac1 = mfma16(av, wbh[kk], ac1); ac3 = mfma16(av, wbl[kk], ac3); }
        else        { ac0 = mfma16(av, wbh[kk], ac0); ac2 = mfma16(av, wbl[kk], ac2); }
    }
}

// Round 16 = round 14 (producer/consumer, verified 5249 us) + ONE concept:
// both __syncthreads (which compile to s_waitcnt vmcnt(0)+s_barrier, each
// serially draining a just-issued store's coherent ack) become raw s_barrier
// with lgkmcnt(0) only. Store acks now overlap the next poll's load RTT.
// Protocol repair: progress published at step t is t-1 (all waves' re-zeros
// of slot t-1 were drained by their own poll(t) vmcnt(0); barrier#1 orders
// those drains before the publish), so the producer can never overwrite a
// slot whose re-zero is still in flight. DEPTH=8 absorbs the extra step.
__global__ void __launch_bounds__(256, 1)
lstm_pk(const float* __restrict__ x,    // (32,1024,512) fp32
        const float* __restrict__ h0,   // (32,512)
        const float* __restrict__ Wx,   // (512,2048)
        const float* __restrict__ Wh,   // (512,2048)
        const float* __restrict__ bias, // (2048)
        float* __restrict__ out,        // (32,1024,512) fp32, zeroed at launch
        unsigned short* __restrict__ ws16,   // 32x512 bf16 arena (zeroed)
        unsigned* __restrict__ progress,     // 64 words, 32-B spaced (zeroed)
        float* __restrict__ ring)            // 64*DEPTH*1024 f32 (zeroed)
{
    __shared__ float a_lds[32][36];

    const int tid  = threadIdx.x;
    const bool isprod = (blockIdx.x >= NBLK);
    const int blk  = isprod ? (blockIdx.x - NBLK) : blockIdx.x;
    const int hc0  = blk * 8;
    const int lane = tid & 63;
    const int wid  = tid >> 6;          // 4 waves: wid&1 = m-tile, wid>>1 = n-tile
    const int q    = lane >> 4;
    const int mrow = (wid & 1) * 16 + (lane & 15);
    const int bcol = (wid >> 1) * 16 + (lane & 15);
    const int gcol = (bcol >> 3) * HH + hc0 + (bcol & 7);

    // ---- one-time: role-specific weight B-frags, bf16 hi+lo split ----
    const float* wsrc = isprod ? Wx : Wh;
    bf16x8 wbh[16], wbl[16];
    #pragma unroll
    for (int kk = 0; kk < 16; ++kk) {
        const int kb = kk * 32 + q * 8;
        bf16x8 wh_, wl_;
        #pragma unroll
        for (int j = 0; j < 8; ++j) {
            float w = wsrc[(size_t)(kb + j) * (4 * HH) + gcol];
            __bf16 hi = (__bf16)w;
            wh_[j] = hi;
            wl_[j] = (__bf16)(w - (float)hi);
        }
        wbh[kk] = wh_; wbl[kk] = wl_;
    }

    float* rbase = ring + (size_t)blk * DEPTH * 1024;

    // ================= producer role (unchanged from r14) =================
    if (isprod) {
        const float* xrow0 = x + (size_t)mrow * T_LEN * DD + q * 8;
        unsigned last = 0;
        #pragma unroll 1
        for (int t = 0; t < T_LEN; ++t) {
            while (t >= (int)last + DEPTH) {
                last = __hip_atomic_load(progress + blk * FSTRIDE,
                                         __ATOMIC_RELAXED, __HIP_MEMORY_SCOPE_AGENT);
                if (t >= (int)last + DEPTH) __builtin_amdgcn_s_sleep(8);
            }
            f32x4 a0 = {0,0,0,0}, a1 = {0,0,0,0}, a2 = {0,0,0,0}, a3 = {0,0,0,0};
            xpart_mfma(xrow0 + (size_t)t * DD, wbh, wbl, a0, a1, a2, a3);
            f32x4 s = (a0 + a1) + (a2 + a3);
            unsigned u0 = __float_as_uint(s[0]); if (!u0) u0 = 1u;
            unsigned u1 = __float_as_uint(s[1]); if (!u1) u1 = 1u;
            unsigned u2 = __float_as_uint(s[2]); if (!u2) u2 = 1u;
            unsigned u3 = __float_as_uint(s[3]); if (!u3) u3 = 1u;
            unsigned long long lo = ((unsigned long long)u1 << 32) | u0;
            unsigned long long hi = ((unsigned long long)u3 << 32) | u2;
            unsigned long long* dst =
                (unsigned long long*)(rbase + (size_t)(t & (DEPTH - 1)) * 1024 + tid * 4);
            __hip_atomic_store(dst,     lo, __ATOMIC_RELAXED, __HIP_MEMORY_SCOPE_AGENT);
            __hip_atomic_store(dst + 1, hi, __ATOMIC_RELAXED, __HIP_MEMORY_SCOPE_AGENT);
        }
        return;
    }

    // ================= consumer role =================
    const int gn  = tid >> 3;
    const int glc = tid & 7;
    const float bi  = bias[0 * HH + hc0 + glc];
    const float bf_ = bias[1 * HH + hc0 + glc];
    const float bo  = bias[2 * HH + hc0 + glc];
    const float bg  = bias[3 * HH + hc0 + glc];
    float creg = 0.f;
    const size_t outoff = (size_t)gn * T_LEN * HH + hc0 + glc;

    unsigned short* u16out = (unsigned short*)out;
    const unsigned short* cbase =
        (const unsigned short*)out + 2 * ((size_t)mrow * T_LEN * HH) + q * 8;
    const size_t stash_w = 2 * ((size_t)gn * T_LEN * HH) + (hc0 + glc);
    const unsigned short* wsrd = ws16 + (size_t)mrow * HH + q * 8;
    const size_t ws_w = (size_t)gn * HH + (hc0 + glc);

    #pragma unroll 1
    for (int t = 0; t < T_LEN; ++t) {
        const float* rp = rbase + (size_t)(t & (DEPTH - 1)) * 1024 + tid * 4;
        bf16x8 hfrag[16];
        i32x4 rv;
        if (t == 0) {
            #pragma unroll
            for (int kk = 0; kk < 16; ++kk)
                hfrag[kk] = cvt8(*(const f32x8*)(h0 + (size_t)mrow * HH + kk * 32 + q * 8));
            rv = poll_ring(rp);
        } else {
            i32x4 f[16];
            if (t < T_LEN - 1)
                poll17(cbase + 2 * (size_t)(t + 1) * HH, rp, f, &rv);  // stash of h_{t-1}
            else
                poll17(wsrd, rp, f, &rv);                              // h_{T-2} from arena
            #pragma unroll
            for (int kk = 0; kk < 16; ++kk) hfrag[kk] = *(bf16x8*)&f[kk];
        }

        // ---- h-part MFMAs (x-part arrives via ring) ----
        f32x4 ac0 = {0,0,0,0}, ac1 = {0,0,0,0}, ac2 = {0,0,0,0}, ac3 = {0,0,0,0};
        #pragma unroll
        for (int kk = 0; kk < 16; ++kk) {
            if (kk & 1) { ac1 = mfma16(hfrag[kk], wbh[kk], ac1); ac3 = mfma16(hfrag[kk], wbl[kk], ac3); }
            else        { ac0 = mfma16(hfrag[kk], wbh[kk], ac0); ac2 = mfma16(hfrag[kk], wbl[kk], ac2); }
        }
        f32x4 av4 = (ac0 + ac1) + (ac2 + ac3);
        av4[0] += __uint_as_float(rv[0]);
        av4[1] += __uint_as_float(rv[1]);
        av4[2] += __uint_as_float(rv[2]);
        av4[3] += __uint_as_float(rv[3]);

        // ---- re-zero the consumed ring slot (ack rides to next poll's
        // vmcnt(0); globally visible before progress can reach t) ----
        {
            unsigned long long* zp = (unsigned long long*)rp;
            __hip_atomic_store(zp,     0ull, __ATOMIC_RELAXED, __HIP_MEMORY_SCOPE_AGENT);
            __hip_atomic_store(zp + 1, 0ull, __ATOMIC_RELAXED, __HIP_MEMORY_SCOPE_AGENT);
        }

        lds_barrier();                   // (1) gates(t-1) done reading a_lds
                                         //     + all waves passed poll(t)
        if (tid == 0 && t > 0)           // publish t-1: re-zeros of slot t-1
                                         // drained by every wave's poll(t)
            __hip_atomic_store(progress + blk * FSTRIDE, (unsigned)(t - 1),
                               __ATOMIC_RELAXED, __HIP_MEMORY_SCOPE_AGENT);
        #pragma unroll
        for (int r = 0; r < 4; ++r)
            a_lds[(wid & 1) * 16 + q * 4 + r][bcol] = av4[r];
        lds_barrier();                   // (2) a_lds(t) published

        // ---- gates ----
        float ai = a_lds[gn][glc]      + bi;
        float af = a_lds[gn][8 + glc]  + bf_;
        float ao = a_lds[gn][16 + glc] + bo;
        float ag = a_lds[gn][24 + glc] + bg;
        float iv = sigmf_(ai), fv = sigmf_(af), ov = sigmf_(ao);
        float gv = tanhf_(ag);
        creg = fv * creg + iv * gv;
        float hv = ov * tanhf_(creg);

        // ---- pack (intra-wave shuffles; glc = tid&7 so partners same wave) ----
        unsigned hvu = __float_as_uint(hv);
        unsigned long long opair =
            ((unsigned long long)__shfl_xor(hvu, 1) << 32) | (unsigned long long)hvu;
        __bf16 hb = (__bf16)hv;
        unsigned short hus = *(unsigned short*)&hb;
        if (hus == 0) hus = 1;           // +0 -> smallest denormal (poll sentinel)
        unsigned hu = (unsigned)hus;
        unsigned hp = (__shfl_xor(hu, 1) << 16) | hu;
        unsigned long long hq =
            ((unsigned long long)__shfl_xor(hp, 2) << 32) | (unsigned long long)hp;

        // ---- fire-and-forget stores (acks overlap next poll's load RTT) ----
        if ((glc & 1) == 0)
            __hip_atomic_store((unsigned long long*)(out + outoff + (size_t)t * HH),
                               opair, __ATOMIC_RELAXED, __HIP_MEMORY_SCOPE_AGENT);
        if ((glc & 3) == 0) {
            if (t < T_LEN - 2)           // stash h_t into out[:, t+2, :]
                __hip_atomic_store((unsigned long long*)(u16out + stash_w + 2 * (size_t)(t + 2) * HH),
                                   hq, __ATOMIC_RELAXED, __HIP_MEMORY_SCOPE_AGENT);
            else if (t == T_LEN - 2)     // stash h_{T-2} into the d_ws arena
                __hip_atomic_store((unsigned long long*)(ws16 + ws_w),
                                   hq, __ATOMIC_RELAXED, __HIP_MEMORY_SCOPE_AGENT);
        }
    }
}

extern "C" void kernel_launch(void* const* d_in, const int* in_sizes, int n_in,
                              void* d_out, int out_size, void* d_ws, size_t ws_size,
                              hipStream_t stream) {
    const float* x  = (const float*)d_in[0];
    const float* h0 = (const float*)d_in[1];
    const float* Wx = (const float*)d_in[2];
    const float* Wh = (const float*)d_in[3];
    const float* b  = (const float*)d_in[4];
    float* out = (float*)d_out;
    // d_ws layout: [0,32K) h-arena | [32K,34K) progress | [64K, 64K+2M) ring
    unsigned short* ws16 = (unsigned short*)d_ws;
    unsigned* progress   = (unsigned*)((char*)d_ws + 32768);
    float* ring          = (float*)((char*)d_ws + 65536);
    const size_t ring_bytes = (size_t)NBLK * DEPTH * 1024 * sizeof(float);  // 2 MB

    // Self-contained zero-init (data-is-the-flag requires zeroed regions).
    hipMemsetAsync(out, 0, (size_t)32 * T_LEN * HH * sizeof(float), stream);
    hipMemsetAsync(d_ws, 0, 65536 + ring_bytes, stream);
    lstm_pk<<<dim3(2 * NBLK), dim3(256), 0, stream>>>(x, h0, Wx, Wh, b, out,
                                                      ws16, progress, ring);
}